// Round 2
// baseline (443.179 us; speedup 1.0000x reference)
//
#include <hip/hip_runtime.h>
#include <hip/hip_bf16.h>

namespace {
constexpr int kN    = 8192;
constexpr int kFin  = 512;
constexpr int kFout = 64;
constexpr float kAlpha = 0.2f;
constexpr int kJSplit = 8;                  // j-range split for k_attn (wave-level)
constexpr int kJLen   = kN / kJSplit;       // 1024 j per wave
constexpr int kChunks = kJLen / 32;         // 32 chunks of 32 j
constexpr int kTileParts = 2;               // accp partials per 16-row tile (post in-block reduce)

using bf16x8 = __attribute__((ext_vector_type(8))) short;
using f32x4  = __attribute__((ext_vector_type(4))) float;

__device__ __forceinline__ unsigned short f2bf(float x) {
  return __builtin_bit_cast(unsigned short, __float2bfloat16(x));
}
__device__ __forceinline__ float lrelu(float x) {
  return fmaxf(x, kAlpha * x);   // valid since 0<alpha<1
}
// monotone float<->uint order-preserving map (for atomicMax on float)
__device__ __forceinline__ unsigned int fkey(float x) {
  unsigned int b = __float_as_uint(x);
  return (b & 0x80000000u) ? ~b : (b | 0x80000000u);
}
__device__ __forceinline__ float fdec(unsigned int k) {
  return (k & 0x80000000u) ? __uint_as_float(k ^ 0x80000000u) : __uint_as_float(~k);
}
} // namespace

// ---------------------------------------------------------------------------
// k_wt: WT[f][k] = W[k][f]; thread 0 zero-inits the s_dst-max atomic slot.
// ---------------------------------------------------------------------------
__global__ __launch_bounds__(256) void k_wt(const float* __restrict__ W,
                                            float* __restrict__ WT,
                                            unsigned int* __restrict__ Smax_u) {
  const int gid = blockIdx.x * 256 + threadIdx.x;   // 0..32767
  if (gid == 0) *Smax_u = 0u;                       // < fkey(any finite)
  const int k = gid >> 6, f = gid & 63;
  WT[(size_t)f * kFin + k] = W[gid];
}

// ---------------------------------------------------------------------------
// k_linear: h = X@W (fp32); s_src/s_dst (+ global max of s_dst via atomicMax);
// h emitted as hTf in MFMA-B-fragment order:
//   element (jblk*2048 + w*512 + lane*8 + e) = h[jblk*32 + (lane>>4)*8 + e][w*16 + (lane&15)]
// grid 512 x 256. (Unchanged — known-good.)
// ---------------------------------------------------------------------------
__global__ __launch_bounds__(256) void k_linear(
    const float* __restrict__ X, const float* __restrict__ WT, const float* __restrict__ A,
    unsigned short* __restrict__ hTf, float* __restrict__ s_src, float* __restrict__ s_dst,
    unsigned int* __restrict__ Smax_u)
{
  const int t = threadIdx.x;
  const int wv = t >> 6, f = t & 63;
  const int i0 = blockIdx.x * 16;

  __shared__ float Xlds[16 * kFin];          // 32 KB
  __shared__ unsigned short h_sm[16][64];    // 2 KB
  __shared__ float red[4];

  // ---- bulk-stage X tile: 8 outstanding float4 per thread ----
  {
    const float4* Xg = (const float4*)(X + (size_t)i0 * kFin);
    float4* Xl = (float4*)Xlds;
    float4 v0 = Xg[t +   0], v1 = Xg[t + 256], v2 = Xg[t +  512], v3 = Xg[t +  768];
    float4 v4 = Xg[t +1024], v5 = Xg[t +1280], v6 = Xg[t + 1536], v7 = Xg[t + 1792];
    Xl[t +    0] = v0; Xl[t +  256] = v1; Xl[t +  512] = v2; Xl[t +  768] = v3;
    Xl[t + 1024] = v4; Xl[t + 1280] = v5; Xl[t + 1536] = v6; Xl[t + 1792] = v7;
  }
  __syncthreads();

  // ---- compute 4 rows per wave, lane = output feature ----
  const int r0l = wv * 4;                    // local row base
  const float* w0 = WT + (size_t)f * kFin;
  float acc0 = 0.f, acc1 = 0.f, acc2 = 0.f, acc3 = 0.f;
  float4 wb0 = *(const float4*)(w0 + 0);
  float4 wb1 = *(const float4*)(w0 + 4);
  const float* xr = Xlds + r0l * kFin;
  for (int k = 0; k < kFin; k += 4) {
    const float4 wc = (k & 4) ? wb1 : wb0;
    if (k + 8 < kFin) {
      const float4 wn = *(const float4*)(w0 + k + 8);
      if (k & 4) wb1 = wn; else wb0 = wn;
    }
    const float4 xa = *(const float4*)(xr + k);
    const float4 xb = *(const float4*)(xr + kFin + k);
    const float4 xc = *(const float4*)(xr + 2 * kFin + k);
    const float4 xd = *(const float4*)(xr + 3 * kFin + k);
#pragma unroll
    for (int j = 0; j < 4; ++j) {
      const float wk = ((const float*)&wc)[j];
      acc0 = fmaf(((const float*)&xa)[j], wk, acc0);
      acc1 = fmaf(((const float*)&xb)[j], wk, acc1);
      acc2 = fmaf(((const float*)&xc)[j], wk, acc2);
      acc3 = fmaf(((const float*)&xd)[j], wk, acc3);
    }
  }

  // ---- scores + per-wave s_dst max ----
  const float asrc = A[f], adst = A[kFout + f];
  float accs[4] = {acc0, acc1, acc2, acc3};
  float dmax = -3.4e38f;
#pragma unroll
  for (int r = 0; r < 4; ++r) {
    float vs = accs[r] * asrc;
    float vd = accs[r] * adst;
#pragma unroll
    for (int off = 32; off > 0; off >>= 1) {
      vs += __shfl_xor(vs, off, 64);
      vd += __shfl_xor(vd, off, 64);
    }
    if (f == 0) {
      s_src[i0 + r0l + r] = vs;
      s_dst[i0 + r0l + r] = vd;
      dmax = fmaxf(dmax, vd);
    }
    h_sm[r0l + r][f] = f2bf(accs[r]);
  }
  if (f == 0) red[wv] = dmax;
  __syncthreads();
  if (t == 0) {
    float m = fmaxf(fmaxf(red[0], red[1]), fmaxf(red[2], red[3]));
    atomicMax(Smax_u, fkey(m));
  }

  // ---- emit 2 KB hTf fragment slice, coalesced ----
  if (t < 128) {
    const int jblk = i0 >> 5, half = (i0 >> 4) & 1;
    const int w = t >> 5, li = t & 31;
    const int lane = half * 32 + li;
    const int ql = li >> 4, fcol = w * 16 + (li & 15);
    bf16x8 v;
#pragma unroll
    for (int e = 0; e < 8; ++e) v[e] = (short)h_sm[ql * 8 + e][fcol];
    *(bf16x8*)(hTf + (size_t)jblk * 2048 + w * 512 + (size_t)lane * 8) = v;
  }
}

// ---------------------------------------------------------------------------
// k_attn (r7): barrier-free, wave-autonomous main loop.
//
// Each WAVE owns a full 16-row i-tile over a 1024-wide j-octant. Lane l
// computes exactly the MFMA A-fragment elements it feeds:
//     P[row = l&15][k = (l>>4)*8 + e],  e = 0..7   (per 32-j chunk)
// so P never touches LDS and the main loop has NO __syncthreads (a barrier
// would force a vmcnt(0) drain of the depth-2 adj/s_dst prefetch — the r5
// bottleneck). The wave computes all four 16-col output tiles.
//
// The 4 waves of a block share the same tile (wid = 4*blk + wv, tile=wid>>3),
// so partials are reduced in LDS post-loop: accp is 4 MB (1024 x 16 x 64),
// keeping total workspace ~5.5 MB (< 9.4 MB known-good footprint).
// grid 1024 x 256 = 4096 waves = one full-occupancy round at 16 waves/CU.
// ---------------------------------------------------------------------------
__global__ __launch_bounds__(256) void k_attn(
    const int* __restrict__ adj, const unsigned short* __restrict__ hTf,
    const float* __restrict__ s_src, const float* __restrict__ s_dst,
    const unsigned int* __restrict__ Smax_u, float* __restrict__ accp,
    float* __restrict__ lp)
{
  const int t = threadIdx.x;
  const int wv = t >> 6, lane = t & 63;
  const int wid = blockIdx.x * 4 + wv;             // 0..4095
  const int tile = wid >> 3;                       // 0..511 (16-row tile)
  const int q    = wid & 7;                        // j-octant
  const int i0 = tile * 16, jbase = q * kJLen;
  const int row = lane & 15, quad = lane >> 4;

  __shared__ float sacc[4][16][64];                // 16 KB
  __shared__ float sl[4][16];                      // 256 B

  const float S = fdec(*Smax_u);
  const float ssrc = s_src[i0 + row];
  const float mr = lrelu(ssrc + S);                // >= every score in the row

  // per-lane streams: adj[i0+row][jbase + c*32 + quad*8 + (0..7)]
  const int4*   aptr = (const int4*)(adj + (size_t)(i0 + row) * kN + jbase + quad * 8);
  const float4* dptr = (const float4*)(s_dst + jbase + quad * 8);
  const unsigned short* hbase = hTf + (size_t)(jbase >> 5) * 2048 + (size_t)lane * 8;

  float l_acc = 0.f;
  f32x4 acc0 = {0.f, 0.f, 0.f, 0.f};
  f32x4 acc1 = {0.f, 0.f, 0.f, 0.f};
  f32x4 acc2 = {0.f, 0.f, 0.f, 0.f};
  f32x4 acc3 = {0.f, 0.f, 0.f, 0.f};

  // depth-2 prefetch, named registers (no runtime-indexed arrays — scratch!)
  int4   Aa0 = aptr[0],  Aa1 = aptr[1];
  float4 Da0 = dptr[0],  Da1 = dptr[1];
  int4   Ab0 = aptr[8],  Ab1 = aptr[9];
  float4 Db0 = dptr[8],  Db1 = dptr[9];

  auto body = [&](int c, int4& A0, int4& A1, float4& D0, float4& D1)
      __attribute__((always_inline)) {
    // B-fragments for this chunk (L2-resident; issued early, used at MFMA)
    const unsigned short* hp = hbase + (size_t)c * 2048;
    const uint4 hv0 = *(const uint4*)(hp +    0);
    const uint4 hv1 = *(const uint4*)(hp +  512);
    const uint4 hv2 = *(const uint4*)(hp + 1024);
    const uint4 hv3 = *(const uint4*)(hp + 1536);

    float pv[8];
    {
      const int*   aa = (const int*)&A0;
      const float* dd = (const float*)&D0;
#pragma unroll
      for (int j = 0; j < 4; ++j) {
        const float e = lrelu(ssrc + dd[j]);
        pv[j] = aa[j] > 0 ? __expf(e - mr) : 0.f;
      }
      aa = (const int*)&A1; dd = (const float*)&D1;
#pragma unroll
      for (int j = 0; j < 4; ++j) {
        const float e = lrelu(ssrc + dd[j]);
        pv[4 + j] = aa[j] > 0 ? __expf(e - mr) : 0.f;
      }
    }

    // depth-2 rotate: prefetch chunk c+2 into this body's registers.
    // (&31 wraps the final prefetch harmlessly back to chunk 0/1)
    {
      const int cn = (c + 2) & (kChunks - 1);
      A0 = aptr[cn * 8];  A1 = aptr[cn * 8 + 1];
      D0 = dptr[cn * 8];  D1 = dptr[cn * 8 + 1];
    }

    // row-sum (tree) + pack to A-fragment bf16x8 — already in fragment layout
    l_acc += ((pv[0] + pv[1]) + (pv[2] + pv[3])) +
             ((pv[4] + pv[5]) + (pv[6] + pv[7]));
    bf16x8 pa;
#pragma unroll
    for (int j = 0; j < 8; ++j) pa[j] = (short)f2bf(pv[j]);

    acc0 = __builtin_amdgcn_mfma_f32_16x16x32_bf16(pa, __builtin_bit_cast(bf16x8, hv0), acc0, 0, 0, 0);
    acc1 = __builtin_amdgcn_mfma_f32_16x16x32_bf16(pa, __builtin_bit_cast(bf16x8, hv1), acc1, 0, 0, 0);
    acc2 = __builtin_amdgcn_mfma_f32_16x16x32_bf16(pa, __builtin_bit_cast(bf16x8, hv2), acc2, 0, 0, 0);
    acc3 = __builtin_amdgcn_mfma_f32_16x16x32_bf16(pa, __builtin_bit_cast(bf16x8, hv3), acc3, 0, 0, 0);
  };

  for (int c = 0; c < kChunks; c += 2) {
    body(c,     Aa0, Aa1, Da0, Da1);
    body(c + 1, Ab0, Ab1, Db0, Db1);
  }

  // partial denominator: combine the 4 quads of each row
  float lv = l_acc;
  lv += __shfl_xor(lv, 16, 64);
  lv += __shfl_xor(lv, 32, 64);
  if (lane < 16) sl[wv][lane] = lv;

  // stage this wave's PV tile to LDS: [i_local = quad*4+reg][f = g*16+row]
  {
    float* ab = &sacc[wv][0][0];
#pragma unroll
    for (int reg = 0; reg < 4; ++reg) {
      ab[(quad * 4 + reg) * 64 +  0 + row] = acc0[reg];
      ab[(quad * 4 + reg) * 64 + 16 + row] = acc1[reg];
      ab[(quad * 4 + reg) * 64 + 32 + row] = acc2[reg];
      ab[(quad * 4 + reg) * 64 + 48 + row] = acc3[reg];
    }
  }
  __syncthreads();   // post-loop only; nothing left to prefetch

  // cross-wave reduce (4 partials) and single coalesced store per block
  {
    const float* sb = &sacc[0][0][0];
    float* gout = accp + (size_t)blockIdx.x * 16 * 64;
#pragma unroll
    for (int k = 0; k < 4; ++k) {
      const int idx = t + k * 256;
      gout[idx] = (sb[idx] + sb[1024 + idx]) + (sb[2048 + idx] + sb[3072 + idx]);
    }
    if (t < 16) {
      lp[(size_t)blockIdx.x * 16 + t] =
          (sl[0][t] + sl[1][t]) + (sl[2][t] + sl[3][t]);
    }
  }
}

// ---------------------------------------------------------------------------
// k_comb: out[i][f] = elu( (sum_p accp) / (sum_p lp) ), 2 partials per tile
// ---------------------------------------------------------------------------
__global__ __launch_bounds__(256) void k_comb(const float* __restrict__ accp,
                                              const float* __restrict__ lp,
                                              float* __restrict__ out)
{
  const int gid = blockIdx.x * 256 + threadIdx.x;   // 0..524287
  const int i = gid >> 6, f = gid & 63;
  const int ib = i >> 4, il = i & 15;
  const int b0 = ib * kTileParts;
  float a = 0.f, l = 0.f;
#pragma unroll
  for (int p = 0; p < kTileParts; ++p) {
    a += accp[((size_t)(b0 + p) * 16 + il) * 64 + f];
    l += lp[(size_t)(b0 + p) * 16 + il];
  }
  float v = a / l;
  v = v > 0.f ? v : __expf(v) - 1.f;
  out[gid] = v;
}

extern "C" void kernel_launch(void* const* d_in, const int* in_sizes, int n_in,
                              void* d_out, int out_size, void* d_ws, size_t ws_size,
                              hipStream_t stream) {
  const float* X   = (const float*)d_in[0];   // [8192][512]
  const int*   adj = (const int*)d_in[1];     // [8192][8192]
  const float* W   = (const float*)d_in[2];   // [512][64]
  const float* A   = (const float*)d_in[3];   // [128]
  float* out = (float*)d_out;                 // [8192][64] fp32

  char* ws = (char*)d_ws;
  unsigned short* hTf = (unsigned short*)ws;  ws += (size_t)kN * kFout * 2;    // 1 MB
  float* WT    = (float*)ws;                  ws += (size_t)kFout * kFin * 4;  // 128 KB
  float* s_src = (float*)ws;                  ws += kN * 4;
  float* s_dst = (float*)ws;                  ws += kN * 4;
  unsigned int* Smax_u = (unsigned int*)ws;   ws += 256;
  float* accp  = (float*)ws;                  ws += (size_t)(kN / 16) * kTileParts * 16 * 64 * 4; // 4 MB
  float* lp    = (float*)ws;                  // 64 KB

  k_wt    <<<kFin * kFout / 256, 256, 0, stream>>>(W, WT, Smax_u);
  k_linear<<<kN / 16, 256, 0, stream>>>(X, WT, A, hTf, s_src, s_dst, Smax_u);
  k_attn  <<<(kN / 16) * kJSplit / 4, 256, 0, stream>>>(adj, hTf, s_src, s_dst, Smax_u, accp, lp);
  k_comb  <<<kN * kFout / 256, 256, 0, stream>>>(accp, lp, out);
}

// Round 3
// 430.673 us; speedup vs baseline: 1.0290x; 1.0290x over previous
//
#include <hip/hip_runtime.h>
#include <hip/hip_bf16.h>

namespace {
constexpr int kN    = 8192;
constexpr int kFin  = 512;
constexpr int kFout = 64;
constexpr float kAlpha = 0.2f;
constexpr int kJSplit = 8;                  // j-range split for k_attn (wave-level)
constexpr int kJLen   = kN / kJSplit;       // 1024 j per wave
constexpr int kChunks = kJLen / 32;         // 32 chunks of 32 j
constexpr int kTileParts = 2;               // accp partials per 16-row tile

using bf16x4 = __attribute__((ext_vector_type(4))) short;
using bf16x8 = __attribute__((ext_vector_type(8))) short;
using f32x4  = __attribute__((ext_vector_type(4))) float;

__device__ __forceinline__ unsigned short f2bf(float x) {
  return __builtin_bit_cast(unsigned short, __float2bfloat16(x));
}
__device__ __forceinline__ float lrelu(float x) {
  return fmaxf(x, kAlpha * x);   // valid since 0<alpha<1
}
// monotone float<->uint order-preserving map (for atomicMax on float)
__device__ __forceinline__ unsigned int fkey(float x) {
  unsigned int b = __float_as_uint(x);
  return (b & 0x80000000u) ? ~b : (b | 0x80000000u);
}
__device__ __forceinline__ float fdec(unsigned int k) {
  return (k & 0x80000000u) ? __uint_as_float(k ^ 0x80000000u) : __uint_as_float(~k);
}
} // namespace

// ---------------------------------------------------------------------------
// k_wt: WT[f][k] = W[k][f]; thread 0 zero-inits the s_dst-max atomic slot.
// ---------------------------------------------------------------------------
__global__ __launch_bounds__(256) void k_wt(const float* __restrict__ W,
                                            float* __restrict__ WT,
                                            unsigned int* __restrict__ Smax_u) {
  const int gid = blockIdx.x * 256 + threadIdx.x;   // 0..32767
  if (gid == 0) *Smax_u = 0u;                       // < fkey(any finite)
  const int k = gid >> 6, f = gid & 63;
  WT[(size_t)f * kFin + k] = W[gid];
}

// ---------------------------------------------------------------------------
// k_linear: h = X@W (fp32); s_src/s_dst (+ global max of s_dst via atomicMax);
// h emitted as hTf in MFMA-B-fragment order. grid 512 x 256. (Known-good.)
// ---------------------------------------------------------------------------
__global__ __launch_bounds__(256) void k_linear(
    const float* __restrict__ X, const float* __restrict__ WT, const float* __restrict__ A,
    unsigned short* __restrict__ hTf, float* __restrict__ s_src, float* __restrict__ s_dst,
    unsigned int* __restrict__ Smax_u)
{
  const int t = threadIdx.x;
  const int wv = t >> 6, f = t & 63;
  const int i0 = blockIdx.x * 16;

  __shared__ float Xlds[16 * kFin];          // 32 KB
  __shared__ unsigned short h_sm[16][64];    // 2 KB
  __shared__ float red[4];

  // ---- bulk-stage X tile: 8 outstanding float4 per thread ----
  {
    const float4* Xg = (const float4*)(X + (size_t)i0 * kFin);
    float4* Xl = (float4*)Xlds;
    float4 v0 = Xg[t +   0], v1 = Xg[t + 256], v2 = Xg[t +  512], v3 = Xg[t +  768];
    float4 v4 = Xg[t +1024], v5 = Xg[t +1280], v6 = Xg[t + 1536], v7 = Xg[t + 1792];
    Xl[t +    0] = v0; Xl[t +  256] = v1; Xl[t +  512] = v2; Xl[t +  768] = v3;
    Xl[t + 1024] = v4; Xl[t + 1280] = v5; Xl[t + 1536] = v6; Xl[t + 1792] = v7;
  }
  __syncthreads();

  // ---- compute 4 rows per wave, lane = output feature ----
  const int r0l = wv * 4;                    // local row base
  const float* w0 = WT + (size_t)f * kFin;
  float acc0 = 0.f, acc1 = 0.f, acc2 = 0.f, acc3 = 0.f;
  float4 wb0 = *(const float4*)(w0 + 0);
  float4 wb1 = *(const float4*)(w0 + 4);
  const float* xr = Xlds + r0l * kFin;
  for (int k = 0; k < kFin; k += 4) {
    const float4 wc = (k & 4) ? wb1 : wb0;
    if (k + 8 < kFin) {
      const float4 wn = *(const float4*)(w0 + k + 8);
      if (k & 4) wb1 = wn; else wb0 = wn;
    }
    const float4 xa = *(const float4*)(xr + k);
    const float4 xb = *(const float4*)(xr + kFin + k);
    const float4 xc = *(const float4*)(xr + 2 * kFin + k);
    const float4 xd = *(const float4*)(xr + 3 * kFin + k);
#pragma unroll
    for (int j = 0; j < 4; ++j) {
      const float wk = ((const float*)&wc)[j];
      acc0 = fmaf(((const float*)&xa)[j], wk, acc0);
      acc1 = fmaf(((const float*)&xb)[j], wk, acc1);
      acc2 = fmaf(((const float*)&xc)[j], wk, acc2);
      acc3 = fmaf(((const float*)&xd)[j], wk, acc3);
    }
  }

  // ---- scores + per-wave s_dst max ----
  const float asrc = A[f], adst = A[kFout + f];
  float accs[4] = {acc0, acc1, acc2, acc3};
  float dmax = -3.4e38f;
#pragma unroll
  for (int r = 0; r < 4; ++r) {
    float vs = accs[r] * asrc;
    float vd = accs[r] * adst;
#pragma unroll
    for (int off = 32; off > 0; off >>= 1) {
      vs += __shfl_xor(vs, off, 64);
      vd += __shfl_xor(vd, off, 64);
    }
    if (f == 0) {
      s_src[i0 + r0l + r] = vs;
      s_dst[i0 + r0l + r] = vd;
      dmax = fmaxf(dmax, vd);
    }
    h_sm[r0l + r][f] = f2bf(accs[r]);
  }
  if (f == 0) red[wv] = dmax;
  __syncthreads();
  if (t == 0) {
    float m = fmaxf(fmaxf(red[0], red[1]), fmaxf(red[2], red[3]));
    atomicMax(Smax_u, fkey(m));
  }

  // ---- emit 2 KB hTf fragment slice, coalesced ----
  if (t < 128) {
    const int jblk = i0 >> 5, half = (i0 >> 4) & 1;
    const int w = t >> 5, li = t & 31;
    const int lane = half * 32 + li;
    const int ql = li >> 4, fcol = w * 16 + (li & 15);
    bf16x8 v;
#pragma unroll
    for (int e = 0; e < 8; ++e) v[e] = (short)h_sm[ql * 8 + e][fcol];
    *(bf16x8*)(hTf + (size_t)jblk * 2048 + w * 512 + (size_t)lane * 8) = v;
  }
}

// ---------------------------------------------------------------------------
// k_attn (r8): wave-autonomous, COALESCED adj loads + per-wave LDS P-routing.
//
// r7 lesson: barrier removal didn't help (412->443), so the bottleneck is the
// adj request pattern: r7's load issued 64 discontiguous 16-B pieces per
// instruction (16 rows x 4 interleaved quads). r8 loads adj in LOAD layout:
//   inst A: lane l -> row l>>3 (0-7),  bytes (l&7)*16  => 8 full 128-B lines
//   inst B: same for rows 8-15
// P is computed in load layout (lane owns 4 cols of one row per inst), packed
// to bf16, routed through a per-wave LDS buffer (padded [16][40], fragments
// 16-B aligned), and ds_read_b128 back in MFMA A-fragment order. Within-wave
// write->read needs only lgkmcnt — still NO barriers in the main loop.
// ---------------------------------------------------------------------------
__global__ __launch_bounds__(256, 4) void k_attn(
    const int* __restrict__ adj, const unsigned short* __restrict__ hTf,
    const float* __restrict__ s_src, const float* __restrict__ s_dst,
    const unsigned int* __restrict__ Smax_u, float* __restrict__ accp,
    float* __restrict__ lp)
{
  const int t = threadIdx.x;
  const int wv = t >> 6, lane = t & 63;
  const int wid = blockIdx.x * 4 + wv;             // 0..4095
  const int tile = wid >> 3;                       // 0..511 (16-row tile)
  const int q    = wid & 7;                        // j-octant
  const int i0 = tile * 16, jbase = q * kJLen;
  // load-layout coords
  const int lr = lane >> 3;                        // row within half (0-7)
  const int lg = lane & 7;                         // 4-col group
  // fragment-layout coords
  const int row = lane & 15, quad = lane >> 4;

  __shared__ unsigned short Pl[4][2][16][40];      // 10 KB (padded rows, 80 B)
  __shared__ float sacc[4][16][64];                // 16 KB
  __shared__ float sl[4][16];                      // 256 B

  const float S = fdec(*Smax_u);
  const float sA = s_src[i0 + lr];
  const float sB = s_src[i0 + 8 + lr];
  const float mA = lrelu(sA + S);                  // >= every score in row lr
  const float mB = lrelu(sB + S);

  // per-lane streams (load layout): 8 int4 per row-chunk
  const int4* aA = (const int4*)(adj + (size_t)(i0 + lr) * kN + jbase) + lg;
  const int4* aB = (const int4*)(adj + (size_t)(i0 + 8 + lr) * kN + jbase) + lg;
  const float4* dp = (const float4*)(s_dst + jbase) + lg;
  const unsigned short* hbase = hTf + (size_t)(jbase >> 5) * 2048 + (size_t)lane * 8;

  float l_accA = 0.f, l_accB = 0.f;
  f32x4 acc0 = {0.f, 0.f, 0.f, 0.f};
  f32x4 acc1 = {0.f, 0.f, 0.f, 0.f};
  f32x4 acc2 = {0.f, 0.f, 0.f, 0.f};
  f32x4 acc3 = {0.f, 0.f, 0.f, 0.f};

  // depth-2 prefetch, named registers
  int4   Aa = aA[0], Ba = aB[0];  float4 Da = dp[0];
  int4   Ab = aA[8], Bb = aB[8];  float4 Db = dp[8];

  auto body = [&](int c, int sbuf, int4& A, int4& B, float4& D)
      __attribute__((always_inline)) {
    // B-fragments for this chunk (L2-resident; issued early, used at MFMA)
    const unsigned short* hp = hbase + (size_t)c * 2048;
    const uint4 hv0 = *(const uint4*)(hp +    0);
    const uint4 hv1 = *(const uint4*)(hp +  512);
    const uint4 hv2 = *(const uint4*)(hp + 1024);
    const uint4 hv3 = *(const uint4*)(hp + 1536);

    // P in load layout: 4 cols of row lr (A) and row 8+lr (B)
    float pvA[4], pvB[4];
    {
      const int*   ia = (const int*)&A;
      const int*   ib = (const int*)&B;
      const float* dd = (const float*)&D;
#pragma unroll
      for (int j = 0; j < 4; ++j) {
        const float eA = lrelu(sA + dd[j]);
        const float eB = lrelu(sB + dd[j]);
        pvA[j] = ia[j] > 0 ? __expf(eA - mA) : 0.f;
        pvB[j] = ib[j] > 0 ? __expf(eB - mB) : 0.f;
      }
    }
    l_accA += (pvA[0] + pvA[1]) + (pvA[2] + pvA[3]);
    l_accB += (pvB[0] + pvB[1]) + (pvB[2] + pvB[3]);

    // pack + route through per-wave LDS (write 8 B x2, conflict-benign)
    bf16x4 wA, wB;
#pragma unroll
    for (int j = 0; j < 4; ++j) {
      wA[j] = (short)f2bf(pvA[j]);
      wB[j] = (short)f2bf(pvB[j]);
    }
    *(bf16x4*)&Pl[wv][sbuf][lr][lg * 4]     = wA;
    *(bf16x4*)&Pl[wv][sbuf][8 + lr][lg * 4] = wB;

    // depth-2 rotate: prefetch chunk c+2 (wrap harmless)
    {
      const int cn = (c + 2) & (kChunks - 1);
      A = aA[cn * 8];  B = aB[cn * 8];  D = dp[cn * 8];
    }

    // fragment read (16-B aligned, padded stride) + MFMA cluster
    const bf16x8 pa = *(const bf16x8*)&Pl[wv][sbuf][row][quad * 8];
    __builtin_amdgcn_s_setprio(1);
    acc0 = __builtin_amdgcn_mfma_f32_16x16x32_bf16(pa, __builtin_bit_cast(bf16x8, hv0), acc0, 0, 0, 0);
    acc1 = __builtin_amdgcn_mfma_f32_16x16x32_bf16(pa, __builtin_bit_cast(bf16x8, hv1), acc1, 0, 0, 0);
    acc2 = __builtin_amdgcn_mfma_f32_16x16x32_bf16(pa, __builtin_bit_cast(bf16x8, hv2), acc2, 0, 0, 0);
    acc3 = __builtin_amdgcn_mfma_f32_16x16x32_bf16(pa, __builtin_bit_cast(bf16x8, hv3), acc3, 0, 0, 0);
    __builtin_amdgcn_s_setprio(0);
  };

  for (int c = 0; c < kChunks; c += 2) {
    body(c,     0, Aa, Ba, Da);
    body(c + 1, 1, Ab, Bb, Db);
  }

  // denominator: reduce over the 8 col-groups (lanes sharing lr)
  l_accA += __shfl_xor(l_accA, 1, 64);
  l_accA += __shfl_xor(l_accA, 2, 64);
  l_accA += __shfl_xor(l_accA, 4, 64);
  l_accB += __shfl_xor(l_accB, 1, 64);
  l_accB += __shfl_xor(l_accB, 2, 64);
  l_accB += __shfl_xor(l_accB, 4, 64);
  if (lg == 0) {
    sl[wv][lr]     = l_accA;
    sl[wv][8 + lr] = l_accB;
  }

  // stage this wave's PV tile: [i_local = quad*4+reg][f = g*16+row]
  {
    float* ab = &sacc[wv][0][0];
#pragma unroll
    for (int reg = 0; reg < 4; ++reg) {
      ab[(quad * 4 + reg) * 64 +  0 + row] = acc0[reg];
      ab[(quad * 4 + reg) * 64 + 16 + row] = acc1[reg];
      ab[(quad * 4 + reg) * 64 + 32 + row] = acc2[reg];
      ab[(quad * 4 + reg) * 64 + 48 + row] = acc3[reg];
    }
  }
  __syncthreads();   // post-loop only

  // cross-wave reduce (4 partials) and single coalesced store per block
  {
    const float* sb = &sacc[0][0][0];
    float* gout = accp + (size_t)blockIdx.x * 16 * 64;
#pragma unroll
    for (int k = 0; k < 4; ++k) {
      const int idx = t + k * 256;
      gout[idx] = (sb[idx] + sb[1024 + idx]) + (sb[2048 + idx] + sb[3072 + idx]);
    }
    if (t < 16) {
      lp[(size_t)blockIdx.x * 16 + t] =
          (sl[0][t] + sl[1][t]) + (sl[2][t] + sl[3][t]);
    }
  }
}

// ---------------------------------------------------------------------------
// k_comb: out[i][f] = elu( (sum_p accp) / (sum_p lp) ), 2 partials per tile
// ---------------------------------------------------------------------------
__global__ __launch_bounds__(256) void k_comb(const float* __restrict__ accp,
                                              const float* __restrict__ lp,
                                              float* __restrict__ out)
{
  const int gid = blockIdx.x * 256 + threadIdx.x;   // 0..524287
  const int i = gid >> 6, f = gid & 63;
  const int ib = i >> 4, il = i & 15;
  const int b0 = ib * kTileParts;
  float a = 0.f, l = 0.f;
#pragma unroll
  for (int p = 0; p < kTileParts; ++p) {
    a += accp[((size_t)(b0 + p) * 16 + il) * 64 + f];
    l += lp[(size_t)(b0 + p) * 16 + il];
  }
  float v = a / l;
  v = v > 0.f ? v : __expf(v) - 1.f;
  out[gid] = v;
}

extern "C" void kernel_launch(void* const* d_in, const int* in_sizes, int n_in,
                              void* d_out, int out_size, void* d_ws, size_t ws_size,
                              hipStream_t stream) {
  const float* X   = (const float*)d_in[0];   // [8192][512]
  const int*   adj = (const int*)d_in[1];     // [8192][8192]
  const float* W   = (const float*)d_in[2];   // [512][64]
  const float* A   = (const float*)d_in[3];   // [128]
  float* out = (float*)d_out;                 // [8192][64] fp32

  char* ws = (char*)d_ws;
  unsigned short* hTf = (unsigned short*)ws;  ws += (size_t)kN * kFout * 2;    // 1 MB
  float* WT    = (float*)ws;                  ws += (size_t)kFout * kFin * 4;  // 128 KB
  float* s_src = (float*)ws;                  ws += kN * 4;
  float* s_dst = (float*)ws;                  ws += kN * 4;
  unsigned int* Smax_u = (unsigned int*)ws;   ws += 256;
  float* accp  = (float*)ws;                  ws += (size_t)(kN / 16) * kTileParts * 16 * 64 * 4; // 4 MB
  float* lp    = (float*)ws;                  // 64 KB

  k_wt    <<<kFin * kFout / 256, 256, 0, stream>>>(W, WT, Smax_u);
  k_linear<<<kN / 16, 256, 0, stream>>>(X, WT, A, hTf, s_src, s_dst, Smax_u);
  k_attn  <<<(kN / 16) * kJSplit / 4, 256, 0, stream>>>(adj, hTf, s_src, s_dst, Smax_u, accp, lp);
  k_comb  <<<kN * kFout / 256, 256, 0, stream>>>(accp, lp, out);
}